// Round 9
// baseline (272.020 us; speedup 1.0000x reference)
//
#include <hip/hip_runtime.h>
#include <hip/hip_bf16.h>
#include <math.h>

// Problem constants
#define BB 2
#define SS 1024
#define DD 768
#define HH 12
#define DHH 64
#define MM 64
#define DFF 3072
#define BS (BB*SS)          // 2048 rows
#define EPS_LN 1e-5f
#define EPS_PHI 1e-6f
#define CC 64               // scan chunk length
#define NC (SS/CC)          // 16 chunks
#define NQ 3840             // q,k,v (2304) + proj_q (768) + proj_k (768)
#define PQOFF 2304
#define PKOFF 3072
#define VOFF  1536

typedef __hip_bfloat16 bf16;
using v8s = __attribute__((ext_vector_type(8))) short;   // 8 bf16 (MFMA A/B frag)
using v4f = __attribute__((ext_vector_type(4))) float;   // MFMA C/D frag
struct b4 { bf16 v[4]; };                                // 8B packed bf16 quad

// Direct global->LDS 16B async copy (width=16).
typedef const __attribute__((address_space(1))) void ga_void;
typedef __attribute__((address_space(3))) void ls_void;
__device__ __forceinline__ void gload16(const void* g, void* l) {
    __builtin_amdgcn_global_load_lds((ga_void*)g, (ls_void*)l, 16, 0, 0);
}

// ---------------------------------------------------------------------------
// feat kernel: FAVOR+ fused cols + bias. bid<288: feat; bid==288: bias copy
// + zero scan arrival counters (stream-ordered before scan_sums).
// ---------------------------------------------------------------------------
__global__ __launch_bounds__(256) void feat_kernel(const float* __restrict__ w_attn,
                                                   const float* __restrict__ b_attn,
                                                   const float* __restrict__ wfeat,
                                                   bf16* __restrict__ wext_t,
                                                   float* __restrict__ bias_ext,
                                                   int* __restrict__ cnt) {
    __shared__ float wfTm[64][68];  // wfTm[m][d] = scale*wf[m][d]
    __shared__ float Wt[64][68];    // Wt[j][d]   = w_attn[j0+j][base+d]
    int bid = blockIdx.x;
    int t = threadIdx.x;
    if (bid == 288) {
        for (int i = t; i < 3 * DD; i += 256) bias_ext[i] = b_attn[i];
        if (t < BB * HH) cnt[t] = 0;
        return;
    }
    int jb = bid % 12, h = (bid / 12) % 12, isK = bid / 144;
    int j0 = jb * 64;
    int base = isK * DD + h * DHH;
    const float scale = 0.35355339059327373f;  // 64^-0.25
    #pragma unroll
    for (int it = 0; it < 4; it++) {
        int fidx = it * 256 + t;                 // 1024 float4s
        int r = fidx >> 4, dc = (fidx & 15) * 4;
        float4 wv = *(const float4*)&wfeat[r * DHH + dc];
        wfTm[r][dc + 0] = scale * wv.x; wfTm[r][dc + 1] = scale * wv.y;
        wfTm[r][dc + 2] = scale * wv.z; wfTm[r][dc + 3] = scale * wv.w;
        float4 av = *(const float4*)&w_attn[(size_t)(j0 + r) * (3 * DD) + base + dc];
        Wt[r][dc + 0] = av.x; Wt[r][dc + 1] = av.y;
        Wt[r][dc + 2] = av.z; Wt[r][dc + 3] = av.w;
    }
    __syncthreads();
    int jl = t & 63, mg = (t >> 6) * 16;
    v4f acc[16];
    #pragma unroll
    for (int mi = 0; mi < 16; mi++) acc[mi] = {0.f, 0.f, 0.f, 0.f};
    #pragma unroll
    for (int dc = 0; dc < 16; dc++) {
        v4f wv = *(const v4f*)&Wt[jl][dc * 4];
        #pragma unroll
        for (int mi = 0; mi < 16; mi++) {
            v4f fv = *(const v4f*)&wfTm[mg + mi][dc * 4];
            acc[mi] += fv * wv;
        }
    }
    #pragma unroll
    for (int mi = 0; mi < 16; mi++) {
        float s = acc[mi][0] + acc[mi][1] + acc[mi][2] + acc[mi][3];
        wext_t[(size_t)(PQOFF + isK * DD + h * DHH + mg + mi) * DD + j0 + jl] = __float2bfloat16(s);
    }
    if (jb == 0 && t < 64) {
        float accb = 0.f;
        #pragma unroll 8
        for (int d = 0; d < 64; d++) accb += wfTm[t][d] * b_attn[base + d];
        bias_ext[PQOFF + isK * DD + h * DHH + t] = accb;
    }
}

// ---------------------------------------------------------------------------
// prep_main: LN1 (bid<2048) + BW-shaped transposes (2048..3775). 16.9KB LDS.
// ---------------------------------------------------------------------------
__global__ __launch_bounds__(256) void prep_main(const float* __restrict__ x,
                                                 const float* __restrict__ ln1_g,
                                                 const float* __restrict__ ln1_b,
                                                 const float* __restrict__ w_attn,
                                                 const float* __restrict__ w_proj,
                                                 const float* __restrict__ w_fc,
                                                 const float* __restrict__ w_out,
                                                 bf16* __restrict__ a_bf,
                                                 bf16* __restrict__ wext_t,
                                                 bf16* __restrict__ wproj_t,
                                                 bf16* __restrict__ wfc_t,
                                                 bf16* __restrict__ wout_t) {
    __shared__ float smem[64 * 65];   // 16.6 KB
    int bid = blockIdx.x;
    int t = threadIdx.x;
    if (bid < 2048) {
        // --- LN1 path ---
        int row = bid;
        const float* xr = x + (size_t)row * DD;
        float v0 = xr[t], v1 = xr[t + 256], v2 = xr[t + 512];
        float s = v0 + v1 + v2;
        float s2 = v0 * v0 + v1 * v1 + v2 * v2;
        #pragma unroll
        for (int off = 32; off > 0; off >>= 1) {
            s  += __shfl_xor(s,  off, 64);
            s2 += __shfl_xor(s2, off, 64);
        }
        float* ls = smem; float* ls2 = smem + 4;
        if ((t & 63) == 0) { ls[t >> 6] = s; ls2[t >> 6] = s2; }
        __syncthreads();
        s  = ls[0] + ls[1] + ls[2] + ls[3];
        s2 = ls2[0] + ls2[1] + ls2[2] + ls2[3];
        float mu  = s * (1.0f / DD);
        float var = s2 * (1.0f / DD) - mu * mu;
        float r = rsqrtf(var + EPS_LN);
        bf16* orow = a_bf + (size_t)row * DD;
        orow[t]       = __float2bfloat16((v0 - mu) * r * ln1_g[t]       + ln1_b[t]);
        orow[t + 256] = __float2bfloat16((v1 - mu) * r * ln1_g[t + 256] + ln1_b[t + 256]);
        orow[t + 512] = __float2bfloat16((v2 - mu) * r * ln1_g[t + 512] + ln1_b[t + 512]);
    } else {
        int b = bid - 2048;
        const float* in; bf16* outp; int K, N, xt, yt;
        if (b < 432)       { in = w_attn; outp = wext_t;  K = 768;  N = 2304; xt = b % 36; yt = b / 36; }
        else if (b < 576)  { int b1 = b - 432;  in = w_proj; outp = wproj_t; K = 768;  N = 768;  xt = b1 % 12; yt = b1 / 12; }
        else if (b < 1152) { int b1 = b - 576;  in = w_fc;   outp = wfc_t;   K = 768;  N = 3072; xt = b1 % 48; yt = b1 / 48; }
        else               { int b1 = b - 1152; in = w_out;  outp = wout_t;  K = 3072; N = 768;  xt = b1 % 12; yt = b1 / 12; }
        float (*sm)[65] = (float(*)[65])smem;
        int n0 = xt * 64, k0 = yt * 64;
        int rr = t >> 4, cc = (t & 15) * 4;
        #pragma unroll
        for (int it = 0; it < 4; it++) {
            int kr = it * 16 + rr;
            float4 v = *(const float4*)&in[(size_t)(k0 + kr) * N + n0 + cc];
            sm[kr][cc + 0] = v.x; sm[kr][cc + 1] = v.y;
            sm[kr][cc + 2] = v.z; sm[kr][cc + 3] = v.w;
        }
        __syncthreads();
        #pragma unroll
        for (int it = 0; it < 4; it++) {
            int nr = it * 16 + rr;
            b4 o;
            #pragma unroll
            for (int j = 0; j < 4; j++) o.v[j] = __float2bfloat16(sm[cc + j][nr]);
            *(b4*)&outp[(size_t)(n0 + nr) * K + k0 + cc] = o;
        }
    }
}

// ---------------------------------------------------------------------------
// LayerNorm (LN2): one block per row, 256 threads; f32 in -> bf16 out.
// ---------------------------------------------------------------------------
__global__ __launch_bounds__(256) void ln_kernel(const float* __restrict__ x,
                                                 const float* __restrict__ g,
                                                 const float* __restrict__ bta,
                                                 bf16* __restrict__ out) {
    int row = blockIdx.x;
    int t = threadIdx.x;
    const float* xr = x + (size_t)row * DD;
    float v0 = xr[t], v1 = xr[t + 256], v2 = xr[t + 512];
    float s = v0 + v1 + v2;
    float s2 = v0 * v0 + v1 * v1 + v2 * v2;
    #pragma unroll
    for (int off = 32; off > 0; off >>= 1) {
        s  += __shfl_xor(s,  off, 64);
        s2 += __shfl_xor(s2, off, 64);
    }
    __shared__ float ls[4], ls2[4];
    if ((t & 63) == 0) { ls[t >> 6] = s; ls2[t >> 6] = s2; }
    __syncthreads();
    s  = ls[0] + ls[1] + ls[2] + ls[3];
    s2 = ls2[0] + ls2[1] + ls2[2] + ls2[3];
    float mu  = s * (1.0f / DD);
    float var = s2 * (1.0f / DD) - mu * mu;
    float r = rsqrtf(var + EPS_LN);
    bf16* orow = out + (size_t)row * DD;
    orow[t]       = __float2bfloat16((v0 - mu) * r * g[t]       + bta[t]);
    orow[t + 256] = __float2bfloat16((v1 - mu) * r * g[t + 256] + bta[t + 256]);
    orow[t + 512] = __float2bfloat16((v2 - mu) * r * g[t + 512] + bta[t + 512]);
}

// ---------------------------------------------------------------------------
// 4x4 supertile swizzle.
// ---------------------------------------------------------------------------
__device__ inline void swizzle44(int bid, int nx4, int& bx, int& by) {
    int g = bid >> 4, r = bid & 15;
    bx = (g % nx4) * 4 + (r & 3);
    by = (g / nx4) * 4 + (r >> 2);
}

__device__ inline float gelu_tanh(float x) {
    float x3 = x * x * x;
    float u = 0.7978845608028654f * (x + 0.044715f * x3);
    return 0.5f * x * (1.0f + tanhf(u));
}

// ---------------------------------------------------------------------------
// TM=64 x TN=64, BK=128 GEMM — swizzled gload_lds.
// r24: 2x2 wave decomposition (wave owns 32x32): per kc 2A+2B frag reads
// vs 1A+4B before = 16 vs 20 ds_read_b128 per K-step (-20% LDS pipe), same
// MFMA count/order. SQMODE: each wave emits a HALF-row ||.||^2 partial
// (sqbuf stride 48: [row][hidx*2+half]); scan sums the two halves.
// ---------------------------------------------------------------------------
template <int ACT, int HAS_RES, int OUT_BF16, int SQMODE>
__global__ __launch_bounds__(256) void gemm_k128(const bf16* __restrict__ A,
                                                 const bf16* __restrict__ BT,
                                                 const float* __restrict__ bias,
                                                 const float* __restrict__ res,
                                                 void* __restrict__ Cout,
                                                 int N, int K, int nx4,
                                                 float* __restrict__ sqbuf) {
    __shared__ bf16 Asl[64][128];
    __shared__ bf16 Bsl[64][128];
    int bx, by;
    swizzle44(blockIdx.x, nx4, bx, by);
    int tid = threadIdx.x;
    int m0 = by * 64, n0 = bx * 64;
    int wave = tid >> 6, lane = tid & 63;
    int qm = lane & 15, quad = lane >> 4;
    int srow = lane >> 4;
    int chnk = lane & 15;
    int sce = (chnk ^ srow) * 8;          // i even
    int sco = (chnk ^ (srow + 4)) * 8;    // i odd
    const bf16* ag = A  + (size_t)(m0 + wave * 16 + srow) * K;
    const bf16* bg = BT + (size_t)(n0 + wave * 16 + srow) * K;
    int xr = (qm & 7) << 3;               // read-side XOR (elements)
    int wr = (wave & 1) * 32, wc = (wave >> 1) * 32;

    v4f acc[2][2] = {{{0.f,0.f,0.f,0.f},{0.f,0.f,0.f,0.f}},
                     {{0.f,0.f,0.f,0.f},{0.f,0.f,0.f,0.f}}};

    for (int k0 = 0; k0 < K; k0 += 128) {
        __syncthreads();
        #pragma unroll
        for (int i = 0; i < 4; i++) {
            int sc = (i & 1) ? sco : sce;
            gload16(ag + (size_t)(4 * i) * K + k0 + sc, &Asl[wave * 16 + 4 * i][0]);
            gload16(bg + (size_t)(4 * i) * K + k0 + sc, &Bsl[wave * 16 + 4 * i][0]);
        }
        __syncthreads();
        #pragma unroll
        for (int kc = 0; kc < 4; kc++) {
            int off = (kc * 32 + quad * 8) ^ xr;
            v8s a0 = *(const v8s*)&Asl[wr + qm][off];
            v8s a1 = *(const v8s*)&Asl[wr + 16 + qm][off];
            v8s b0 = *(const v8s*)&Bsl[wc + qm][off];
            v8s b1 = *(const v8s*)&Bsl[wc + 16 + qm][off];
            acc[0][0] = __builtin_amdgcn_mfma_f32_16x16x32_bf16(a0, b0, acc[0][0], 0, 0, 0);
            acc[0][1] = __builtin_amdgcn_mfma_f32_16x16x32_bf16(a0, b1, acc[0][1], 0, 0, 0);
            acc[1][0] = __builtin_amdgcn_mfma_f32_16x16x32_bf16(a1, b0, acc[1][0], 0, 0, 0);
            acc[1][1] = __builtin_amdgcn_mfma_f32_16x16x32_bf16(a1, b1, acc[1][1], 0, 0, 0);
        }
    }

    int col_l = lane & 15;
    if (SQMODE && n0 < 1536) {
        int hidx = n0 >> 6;               // q heads 0..11, k heads 12..23
        int half = wc >> 5;
        #pragma unroll
        for (int m = 0; m < 2; m++) {
            #pragma unroll
            for (int r = 0; r < 4; r++) {
                float hsq = 0.f;
                #pragma unroll
                for (int n = 0; n < 2; n++) {
                    float v = acc[m][n][r] + bias[n0 + wc + n * 16 + col_l];
                    hsq += v * v;
                }
                hsq += __shfl_xor(hsq, 1, 64); hsq += __shfl_xor(hsq, 2, 64);
                hsq += __shfl_xor(hsq, 4, 64); hsq += __shfl_xor(hsq, 8, 64);
                if (col_l == 0) {
                    int row = m0 + wr + m * 16 + quad * 4 + r;
                    sqbuf[(size_t)row * 48 + hidx * 2 + half] = hsq * (1.0f / 16.0f);
                }
            }
        }
        return;
    }
    #pragma unroll
    for (int n = 0; n < 2; n++) {
        int col = n0 + wc + n * 16 + col_l;
        float bcol = bias[col];
        #pragma unroll
        for (int m = 0; m < 2; m++) {
            #pragma unroll
            for (int r = 0; r < 4; r++) {
                int row = m0 + wr + m * 16 + quad * 4 + r;
                float v = acc[m][n][r] + bcol;
                if (ACT == 1) v = gelu_tanh(v);
                if (HAS_RES) v += res[(size_t)row * N + col];
                if (OUT_BF16) ((bf16*)Cout)[(size_t)row * N + col] = __float2bfloat16(v);
                else          ((float*)Cout)[(size_t)row * N + col] = v;
            }
        }
    }
}

// ---------------------------------------------------------------------------
// TM=32 x TN=64, BK=128 GEMM (proj/out, N=768) — gload_lds + XOR swizzle.
// ---------------------------------------------------------------------------
template <int ACT, int HAS_RES, int OUT_BF16>
__global__ __launch_bounds__(256) void gemm_m32_k128(const bf16* __restrict__ A,
                                                     const bf16* __restrict__ BT,
                                                     const float* __restrict__ bias,
                                                     const float* __restrict__ res,
                                                     void* __restrict__ Cout,
                                                     int N, int K, int nx4) {
    __shared__ bf16 Asl[32][128];
    __shared__ bf16 Bsl[64][128];
    int bx, by;
    swizzle44(blockIdx.x, nx4, bx, by);
    int tid = threadIdx.x;
    int m0 = by * 32, n0 = bx * 64;
    int wave = tid >> 6, lane = tid & 63;
    int qm = lane & 15, quad = lane >> 4;
    int rowh = (wave & 1) * 16;
    int colh = (wave >> 1) * 32;
    int srow = lane >> 4;
    int chnk = lane & 15;
    int sce = (chnk ^ srow) * 8;          // i even
    int sco = (chnk ^ (srow + 4)) * 8;    // i odd
    const bf16* ag = A  + (size_t)(m0 + wave * 8  + srow) * K;
    const bf16* bg = BT + (size_t)(n0 + wave * 16 + srow) * K;
    int xr = (qm & 7) << 3;

    v4f acc[2] = {{0.f,0.f,0.f,0.f},{0.f,0.f,0.f,0.f}};

    for (int k0 = 0; k0 < K; k0 += 128) {
        __syncthreads();
        #pragma unroll
        for (int i = 0; i < 2; i++) {
            int sc = (i & 1) ? sco : sce;
            gload16(ag + (size_t)(4 * i) * K + k0 + sc, &Asl[wave * 8 + 4 * i][0]);
        }
        #pragma unroll
        for (int i = 0; i < 4; i++) {
            int sc = (i & 1) ? sco : sce;
            gload16(bg + (size_t)(4 * i) * K + k0 + sc, &Bsl[wave * 16 + 4 * i][0]);
        }
        __syncthreads();
        #pragma unroll
        for (int kc = 0; kc < 4; kc++) {
            v8s a  = *(const v8s*)&Asl[rowh + qm][(kc * 32 + quad * 8) ^ xr];
            v8s b0 = *(const v8s*)&Bsl[colh + qm][(kc * 32 + quad * 8) ^ xr];
            v8s b1 = *(const v8s*)&Bsl[colh + 16 + qm][(kc * 32 + quad * 8) ^ xr];
            acc[0] = __builtin_amdgcn_mfma_f32_16x16x32_bf16(a, b0, acc[0], 0, 0, 0);
            acc[1] = __builtin_amdgcn_mfma_f32_16x16x32_bf16(a, b1, acc[1], 0, 0, 0);
        }
    }

    #pragma unroll
    for (int ct = 0; ct < 2; ct++) {
        int col = n0 + colh + ct * 16 + qm;
        float bcol = bias[col];
        #pragma unroll
        for (int r = 0; r < 4; r++) {
            int row = m0 + rowh + quad * 4 + r;
            float v = acc[ct][r] + bcol;
            if (ACT == 1) v = gelu_tanh(v);
            if (HAS_RES) v += res[(size_t)row * N + col];
            if (OUT_BF16) ((bf16*)Cout)[(size_t)row * N + col] = __float2bfloat16(v);
            else          ((float*)Cout)[(size_t)row * N + col] = v;
        }
    }
}

// ---------------------------------------------------------------------------
// Scan phase 1 (MFMA) + fused exclusive prefix (r24, last-block pattern).
// StateT[d][m] = V^T @ phik ; Sk[m] = col-sum(phik); last block per (b,h)
// (device-scope atomic arrival count, rocPRIM pattern) does the chunk prefix.
// ---------------------------------------------------------------------------
__global__ __launch_bounds__(256) void scan_sums_mfma(const bf16* __restrict__ qkvp,
                                                      const float* __restrict__ sqbuf,
                                                      float* __restrict__ StateT,
                                                      float* __restrict__ Sk,
                                                      int* __restrict__ cnt) {
    int c = blockIdx.x, h = blockIdx.y, b = blockIdx.z;
    int bh = b * HH + h;
    int t = threadIdx.x;
    __shared__ bf16 vt[64][72];   // V^T[d][s]
    __shared__ bf16 kt[64][72];   // phik^T[m][s]
    __shared__ int lastFlag;
    int sr = t >> 4, cq = (t & 15) * 4;
    #pragma unroll
    for (int i = 0; i < 4; i++) {
        int s = sr + 16 * i;
        size_t grow = (size_t)b * SS + c * CC + s;
        size_t rowg = grow * NQ + h * DHH;
        b4 vv = *(const b4*)&qkvp[rowg + VOFF  + cq];
        b4 kp = *(const b4*)&qkvp[rowg + PKOFF + cq];   // proj_k
        float sq = sqbuf[grow * 48 + 24 + h * 2] + sqbuf[grow * 48 + 24 + h * 2 + 1];
        #pragma unroll
        for (int j = 0; j < 4; j++) {
            vt[cq + j][s] = vv.v[j];
            kt[cq + j][s] = __float2bfloat16(
                __expf(__bfloat162float(kp.v[j]) - sq) * 0.125f + EPS_PHI);
        }
    }
    __syncthreads();
    int wave = t >> 6, lane = t & 63, qm = lane & 15, quad = lane >> 4;
    v4f acc[4] = {{0.f,0.f,0.f,0.f},{0.f,0.f,0.f,0.f},{0.f,0.f,0.f,0.f},{0.f,0.f,0.f,0.f}};
    #pragma unroll
    for (int k0 = 0; k0 < 64; k0 += 32) {
        v8s a = *(const v8s*)&vt[wave * 16 + qm][k0 + quad * 8];
        #pragma unroll
        for (int n = 0; n < 4; n++) {
            v8s bb = *(const v8s*)&kt[n * 16 + qm][k0 + quad * 8];
            acc[n] = __builtin_amdgcn_mfma_f32_16x16x32_bf16(a, bb, acc[n], 0, 0, 0);
        }
    }
    float* dst = StateT + ((size_t)bh * NC + c) * 4096;
    int col_l = lane & 15;
    #pragma unroll
    for (int n = 0; n < 4; n++)
        #pragma unroll
        for (int r = 0; r < 4; r++) {
            int d = wave * 16 + quad * 4 + r;
            dst[d * 64 + n * 16 + col_l] = acc[n][r];
        }
    {   // parallel col-sum: 4 threads per m
        int m = t >> 2, j = t & 3;
        float sum = 0.f;
        #pragma unroll
        for (int i2 = 0; i2 < 16; i2++) sum += __bfloat162float(kt[m][j * 16 + i2]);
        sum += __shfl_xor(sum, 1, 64);
        sum += __shfl_xor(sum, 2, 64);
        if (j == 0) Sk[((size_t)bh * NC + c) * 64 + m] = sum;
    }
    // --- fused exclusive prefix: last-arriving block per bh does it ---
    __threadfence();
    if (t == 0) {
        int old = atomicAdd(&cnt[bh], 1);
        lastFlag = (old == NC - 1);
    }
    __syncthreads();
    if (!lastFlag) return;
    __threadfence();
    float* base = StateT + (size_t)bh * NC * 4096;
    float accp[16];
    #pragma unroll
    for (int i = 0; i < 16; i++) accp[i] = 0.f;
    for (int c2 = 0; c2 < NC; c2++) {
        float v[16];
        #pragma unroll
        for (int i = 0; i < 16; i++) v[i] = base[(size_t)c2 * 4096 + t + i * 256];
        #pragma unroll
        for (int i = 0; i < 16; i++) {
            base[(size_t)c2 * 4096 + t + i * 256] = accp[i];
            accp[i] += v[i];
        }
    }
    if (t < 64) {
        size_t b2 = (size_t)bh * NC * 64 + t;
        float a2 = 0.f;
        for (int c2 = 0; c2 < NC; c2++) {
            float v = Sk[b2 + (size_t)c2 * 64];
            Sk[b2 + (size_t)c2 * 64] = a2;
            a2 += v;
        }
    }
}

// ---------------------------------------------------------------------------
// Scan phase 3 (MFMA): phi from proj + precomputed sq; den via VALU.
// acc = phiq@StateT^T + P@V; attn = acc/den.
// ---------------------------------------------------------------------------
__global__ __launch_bounds__(256) void scan_chunk_mfma(const bf16* __restrict__ qkvp,
                                                       const float* __restrict__ sqbuf,
                                                       const float* __restrict__ StateT,
                                                       const float* __restrict__ SkPre,
                                                       bf16* __restrict__ attn) {
    int c = blockIdx.x, h = blockIdx.y, b = blockIdx.z;
    int bh = b * HH + h;
    int t = threadIdx.x;
    __shared__ bf16 qs[64][72];
    __shared__ bf16 ks[64][72];
    __shared__ bf16 vt[64][72];
    __shared__ bf16 stl[64][72];
    __shared__ bf16 P[64][72];
    int sr = t >> 4, cq = (t & 15) * 4;
    const float* stg = StateT + ((size_t)bh * NC + c) * 4096;
    #pragma unroll
    for (int i = 0; i < 4; i++) {
        int s = sr + 16 * i;
        size_t grow = (size_t)b * SS + c * CC + s;
        size_t rowg = grow * NQ + h * DHH;
        b4 qp = *(const b4*)&qkvp[rowg + PQOFF + cq];   // proj_q
        b4 kp = *(const b4*)&qkvp[rowg + PKOFF + cq];   // proj_k
        b4 vv = *(const b4*)&qkvp[rowg + VOFF  + cq];
        float4 sv = *(const float4*)&stg[s * 64 + cq];
        float sqq = sqbuf[grow * 48 + h * 2]      + sqbuf[grow * 48 + h * 2 + 1];
        float sqk = sqbuf[grow * 48 + 24 + h * 2] + sqbuf[grow * 48 + 24 + h * 2 + 1];
        #pragma unroll
        for (int j = 0; j < 4; j++) {
            qs[s][cq + j] = __float2bfloat16(
                __expf(__bfloat162float(qp.v[j]) - sqq) * 0.125f + EPS_PHI);
            ks[s][cq + j] = __float2bfloat16(
                __expf(__bfloat162float(kp.v[j]) - sqk) * 0.125f + EPS_PHI);
            vt[cq + j][s] = vv.v[j];
        }
        stl[s][cq + 0] = __float2bfloat16(sv.x);
        stl[s][cq + 1] = __float2bfloat16(sv.y);
        stl[s][cq + 2] = __float2bfloat16(sv.z);
        stl[s][cq + 3] = __float2bfloat16(sv.w);
    }
    __syncthreads();
    int wave = t >> 6, lane = t & 63, qm = lane & 15, quad = lane >> 4;
    int col_l = lane & 15;
    int row0 = wave * 16;

    v4f a1[4] = {{0.f,0.f,0.f,0.f},{0.f,0.f,0.f,0.f},{0.f,0.f,0.f,0.f},{0.f,0.f,0.f,0.f}};
    #pragma unroll
    for (int k0 = 0; k0 < 64; k0 += 32) {
        v8s a = *(const v8s*)&qs[row0 + qm][k0 + quad * 8];
        #pragma unroll
        for (int n = 0; n < 4; n++) {
            v8s bb = *(const v8s*)&ks[n * 16 + qm][k0 + quad * 8];
            a1[n] = __builtin_amdgcn_mfma_f32_16x16x32_bf16(a, bb, a1[n], 0, 0, 0);
        }
    }
    float denl[4] = {0.f, 0.f, 0.f, 0.f};
    #pragma unroll
    for (int n = 0; n < 4; n++)
        #pragma unroll
        for (int r = 0; r < 4; r++) {
            int row = row0 + quad * 4 + r;
            int col = n * 16 + col_l;
            float v = (col <= row) ? a1[n][r] : 0.f;
            P[row][col] = __float2bfloat16(v);
            denl[r] += v;
        }
    {   // + phiq . SkPre (cross-chunk part); lane handles m = qm*4..qm*4+3
        const float* skp = SkPre + ((size_t)bh * NC + c) * 64;
        float4 sk4 = *(const float4*)&skp[qm * 4];
        #pragma unroll
        for (int r = 0; r < 4; r++) {
            int row = row0 + quad * 4 + r;
            b4 qv = *(const b4*)&qs[row][qm * 4];
            denl[r] += __bfloat162float(qv.v[0]) * sk4.x
                     + __bfloat162float(qv.v[1]) * sk4.y
                     + __bfloat162float(qv.v[2]) * sk4.z
                     + __bfloat162float(qv.v[3]) * sk4.w;
        }
    }
    #pragma unroll
    for (int r = 0; r < 4; r++) {
        denl[r] += __shfl_xor(denl[r], 1, 64);
        denl[r] += __shfl_xor(denl[r], 2, 64);
        denl[r] += __shfl_xor(denl[r], 4, 64);
        denl[r] += __shfl_xor(denl[r], 8, 64);
    }
    v4f acc[4] = {{0.f,0.f,0.f,0.f},{0.f,0.f,0.f,0.f},{0.f,0.f,0.f,0.f},{0.f,0.f,0.f,0.f}};
    #pragma unroll
    for (int k0 = 0; k0 < 64; k0 += 32) {
        v8s aq = *(const v8s*)&qs[row0 + qm][k0 + quad * 8];
        v8s ap = *(const v8s*)&P [row0 + qm][k0 + quad * 8];
        #pragma unroll
        for (int n = 0; n < 4; n++) {
            v8s b1 = *(const v8s*)&stl[n * 16 + qm][k0 + quad * 8];
            v8s b2 = *(const v8s*)&vt [n * 16 + qm][k0 + quad * 8];
            acc[n] = __builtin_amdgcn_mfma_f32_16x16x32_bf16(aq, b1, acc[n], 0, 0, 0);
            acc[n] = __builtin_amdgcn_mfma_f32_16x16x32_bf16(ap, b2, acc[n], 0, 0, 0);
        }
    }
    #pragma unroll
    for (int n = 0; n < 4; n++)
        #pragma unroll
        for (int r = 0; r < 4; r++) {
            int srow = row0 + quad * 4 + r;
            int d = n * 16 + col_l;
            attn[((size_t)b * SS + c * CC + srow) * DD + h * DHH + d] =
                __float2bfloat16(acc[n][r] / denl[r]);
        }
}

// ---------------------------------------------------------------------------
extern "C" void kernel_launch(void* const* d_in, const int* in_sizes, int n_in,
                              void* d_out, int out_size, void* d_ws, size_t ws_size,
                              hipStream_t stream) {
    const float* x      = (const float*)d_in[0];
    const float* ln1_g  = (const float*)d_in[1];
    const float* ln1_b  = (const float*)d_in[2];
    const float* w_attn = (const float*)d_in[3];
    const float* b_attn = (const float*)d_in[4];
    const float* w_feat = (const float*)d_in[5];
    const float* w_proj = (const float*)d_in[6];
    const float* b_proj = (const float*)d_in[7];
    const float* ln2_g  = (const float*)d_in[8];
    const float* ln2_b  = (const float*)d_in[9];
    const float* w_fc   = (const float*)d_in[10];
    const float* b_fc   = (const float*)d_in[11];
    const float* w_out  = (const float*)d_in[12];
    const float* b_out  = (const float*)d_in[13];
    float* out = (float*)d_out;

    // f32 region
    float* ws = (float*)d_ws;
    size_t off = 0;
    float* buf_x1   = ws + off; off += (size_t)BS * DD;            // 1.57M f32
    float* buf_sk   = ws + off; off += (size_t)BB * HH * NC * MM;  // 24.6K
    float* bias_ext = ws + off; off += NQ;
    float* buf_sq   = ws + off; off += (size_t)BS * 48;            // half-row ||.||^2
    int*   buf_cnt  = (int*)(ws + off); off += 32;                 // scan arrivals
    // bf16 region (16B-aligned: preceding counts are multiples of 4)
    bf16* wb = (bf16*)(ws + off);
    size_t boff = 0;
    bf16* buf_qkvp    = wb + boff; boff += (size_t)BS * NQ;        // 7.86M bf16
    bf16* buf_a_bf    = wb + boff; boff += (size_t)BS * DD;
    bf16* buf_attn_bf = wb + boff; boff += (size_t)BS * DD;
    bf16* wext_t      = wb + boff; boff += (size_t)NQ * DD;
    bf16* wproj_t     = wb + boff; boff += (size_t)DD * DD;
    bf16* wfc_t       = wb + boff; boff += (size_t)DFF * DD;
    bf16* wout_t      = wb + boff; boff += (size_t)DD * DFF;
    // Aliases: StateT (1.57M f32) over buf_x1 (x1 written after scan);
    //          fc bf16 (6.29M) over buf_qkvp head (qkvp dead after scan).
    float* buf_skv   = buf_x1;
    bf16*  buf_fc_bf = buf_qkvp;

    // 0a) FAVOR+ fused cols + bias + zero scan counters
    feat_kernel<<<289, 256, 0, stream>>>(w_attn, b_attn, w_feat, wext_t, bias_ext, buf_cnt);
    // 0b) LN1 + transposes
    prep_main<<<3776, 256, 0, stream>>>(x, ln1_g, ln1_b,
                                        w_attn, w_proj, w_fc, w_out,
                                        buf_a_bf, wext_t, wproj_t, wfc_t, wout_t);
    // 1) [qkv | proj] = a @ W_ext + bias_ext; q/k head tiles -> sq halves
    gemm_k128<0, 0, 1, 1><<<1920, 256, 0, stream>>>(
        buf_a_bf, wext_t, bias_ext, nullptr, buf_qkvp, NQ, DD, 15, buf_sq);
    // 2a) per-chunk sums (MFMA) + fused exclusive prefix (last-block)
    scan_sums_mfma<<<dim3(NC, HH, BB), 256, 0, stream>>>(
        buf_qkvp, buf_sq, buf_skv, buf_sk, buf_cnt);
    // 2b) per-chunk masked-MFMA scan -> attn
    scan_chunk_mfma<<<dim3(NC, HH, BB), 256, 0, stream>>>(
        buf_qkvp, buf_sq, buf_skv, buf_sk, buf_attn_bf);
    // 3) x1 = x + attn @ w_proj + b_proj
    gemm_m32_k128<0, 1, 0><<<768, 256, 0, stream>>>(
        buf_attn_bf, wproj_t, b_proj, x, buf_x1, DD, DD, 3);
    // 4) m = LN2(x1) -> bf16
    ln_kernel<<<BS, 256, 0, stream>>>(buf_x1, ln2_g, ln2_b, buf_a_bf);
    // 5) fc = gelu(m @ w_fc + b_fc) -> bf16
    gemm_k128<1, 0, 1, 0><<<1536, 256, 0, stream>>>(
        buf_a_bf, wfc_t, b_fc, nullptr, buf_fc_bf, DFF, DD, 12, nullptr);
    // 6) out = x1 + fc @ w_out + b_out
    gemm_m32_k128<0, 1, 0><<<768, 256, 0, stream>>>(
        buf_fc_bf, wout_t, b_out, buf_x1, out, DD, DFF, 3);
}

// Round 10
// 209.629 us; speedup vs baseline: 1.2976x; 1.2976x over previous
//
#include <hip/hip_runtime.h>
#include <hip/hip_bf16.h>
#include <math.h>

// Problem constants
#define BB 2
#define SS 1024
#define DD 768
#define HH 12
#define DHH 64
#define MM 64
#define DFF 3072
#define BS (BB*SS)          // 2048 rows
#define EPS_LN 1e-5f
#define EPS_PHI 1e-6f
#define CC 64               // scan chunk length
#define NC (SS/CC)          // 16 chunks
#define NQ 3840             // q,k,v (2304) + proj_q (768) + proj_k (768)
#define PQOFF 2304
#define PKOFF 3072
#define VOFF  1536

typedef __hip_bfloat16 bf16;
using v8s = __attribute__((ext_vector_type(8))) short;   // 8 bf16 (MFMA A/B frag)
using v4f = __attribute__((ext_vector_type(4))) float;   // MFMA C/D frag
struct b4 { bf16 v[4]; };                                // 8B packed bf16 quad

// Direct global->LDS 16B async copy (width=16).
typedef const __attribute__((address_space(1))) void ga_void;
typedef __attribute__((address_space(3))) void ls_void;
__device__ __forceinline__ void gload16(const void* g, void* l) {
    __builtin_amdgcn_global_load_lds((ga_void*)g, (ls_void*)l, 16, 0, 0);
}

// ---------------------------------------------------------------------------
// feat kernel: FAVOR+ fused cols + bias. bid<288: feat; bid==288: bias copy.
// (r25: dropped scan counters — fused last-block prefix REVERTED; r24
// post-mortem: per-block device __threadfence across 8 non-coherent XCD L2s
// + 24 serial RMW chains = scan_sums 3us -> 80us.)
// ---------------------------------------------------------------------------
__global__ __launch_bounds__(256) void feat_kernel(const float* __restrict__ w_attn,
                                                   const float* __restrict__ b_attn,
                                                   const float* __restrict__ wfeat,
                                                   bf16* __restrict__ wext_t,
                                                   float* __restrict__ bias_ext) {
    __shared__ float wfTm[64][68];  // wfTm[m][d] = scale*wf[m][d]
    __shared__ float Wt[64][68];    // Wt[j][d]   = w_attn[j0+j][base+d]
    int bid = blockIdx.x;
    int t = threadIdx.x;
    if (bid == 288) {
        for (int i = t; i < 3 * DD; i += 256) bias_ext[i] = b_attn[i];
        return;
    }
    int jb = bid % 12, h = (bid / 12) % 12, isK = bid / 144;
    int j0 = jb * 64;
    int base = isK * DD + h * DHH;
    const float scale = 0.35355339059327373f;  // 64^-0.25
    #pragma unroll
    for (int it = 0; it < 4; it++) {
        int fidx = it * 256 + t;                 // 1024 float4s
        int r = fidx >> 4, dc = (fidx & 15) * 4;
        float4 wv = *(const float4*)&wfeat[r * DHH + dc];
        wfTm[r][dc + 0] = scale * wv.x; wfTm[r][dc + 1] = scale * wv.y;
        wfTm[r][dc + 2] = scale * wv.z; wfTm[r][dc + 3] = scale * wv.w;
        float4 av = *(const float4*)&w_attn[(size_t)(j0 + r) * (3 * DD) + base + dc];
        Wt[r][dc + 0] = av.x; Wt[r][dc + 1] = av.y;
        Wt[r][dc + 2] = av.z; Wt[r][dc + 3] = av.w;
    }
    __syncthreads();
    int jl = t & 63, mg = (t >> 6) * 16;
    v4f acc[16];
    #pragma unroll
    for (int mi = 0; mi < 16; mi++) acc[mi] = {0.f, 0.f, 0.f, 0.f};
    #pragma unroll
    for (int dc = 0; dc < 16; dc++) {
        v4f wv = *(const v4f*)&Wt[jl][dc * 4];
        #pragma unroll
        for (int mi = 0; mi < 16; mi++) {
            v4f fv = *(const v4f*)&wfTm[mg + mi][dc * 4];
            acc[mi] += fv * wv;
        }
    }
    #pragma unroll
    for (int mi = 0; mi < 16; mi++) {
        float s = acc[mi][0] + acc[mi][1] + acc[mi][2] + acc[mi][3];
        wext_t[(size_t)(PQOFF + isK * DD + h * DHH + mg + mi) * DD + j0 + jl] = __float2bfloat16(s);
    }
    if (jb == 0 && t < 64) {
        float accb = 0.f;
        #pragma unroll 8
        for (int d = 0; d < 64; d++) accb += wfTm[t][d] * b_attn[base + d];
        bias_ext[PQOFF + isK * DD + h * DHH + t] = accb;
    }
}

// ---------------------------------------------------------------------------
// prep_main: LN1 (bid<2048) + BW-shaped transposes (2048..3775). 16.9KB LDS.
// ---------------------------------------------------------------------------
__global__ __launch_bounds__(256) void prep_main(const float* __restrict__ x,
                                                 const float* __restrict__ ln1_g,
                                                 const float* __restrict__ ln1_b,
                                                 const float* __restrict__ w_attn,
                                                 const float* __restrict__ w_proj,
                                                 const float* __restrict__ w_fc,
                                                 const float* __restrict__ w_out,
                                                 bf16* __restrict__ a_bf,
                                                 bf16* __restrict__ wext_t,
                                                 bf16* __restrict__ wproj_t,
                                                 bf16* __restrict__ wfc_t,
                                                 bf16* __restrict__ wout_t) {
    __shared__ float smem[64 * 65];   // 16.6 KB
    int bid = blockIdx.x;
    int t = threadIdx.x;
    if (bid < 2048) {
        // --- LN1 path ---
        int row = bid;
        const float* xr = x + (size_t)row * DD;
        float v0 = xr[t], v1 = xr[t + 256], v2 = xr[t + 512];
        float s = v0 + v1 + v2;
        float s2 = v0 * v0 + v1 * v1 + v2 * v2;
        #pragma unroll
        for (int off = 32; off > 0; off >>= 1) {
            s  += __shfl_xor(s,  off, 64);
            s2 += __shfl_xor(s2, off, 64);
        }
        float* ls = smem; float* ls2 = smem + 4;
        if ((t & 63) == 0) { ls[t >> 6] = s; ls2[t >> 6] = s2; }
        __syncthreads();
        s  = ls[0] + ls[1] + ls[2] + ls[3];
        s2 = ls2[0] + ls2[1] + ls2[2] + ls2[3];
        float mu  = s * (1.0f / DD);
        float var = s2 * (1.0f / DD) - mu * mu;
        float r = rsqrtf(var + EPS_LN);
        bf16* orow = a_bf + (size_t)row * DD;
        orow[t]       = __float2bfloat16((v0 - mu) * r * ln1_g[t]       + ln1_b[t]);
        orow[t + 256] = __float2bfloat16((v1 - mu) * r * ln1_g[t + 256] + ln1_b[t + 256]);
        orow[t + 512] = __float2bfloat16((v2 - mu) * r * ln1_g[t + 512] + ln1_b[t + 512]);
    } else {
        int b = bid - 2048;
        const float* in; bf16* outp; int K, N, xt, yt;
        if (b < 432)       { in = w_attn; outp = wext_t;  K = 768;  N = 2304; xt = b % 36; yt = b / 36; }
        else if (b < 576)  { int b1 = b - 432;  in = w_proj; outp = wproj_t; K = 768;  N = 768;  xt = b1 % 12; yt = b1 / 12; }
        else if (b < 1152) { int b1 = b - 576;  in = w_fc;   outp = wfc_t;   K = 768;  N = 3072; xt = b1 % 48; yt = b1 / 48; }
        else               { int b1 = b - 1152; in = w_out;  outp = wout_t;  K = 3072; N = 768;  xt = b1 % 12; yt = b1 / 12; }
        float (*sm)[65] = (float(*)[65])smem;
        int n0 = xt * 64, k0 = yt * 64;
        int rr = t >> 4, cc = (t & 15) * 4;
        #pragma unroll
        for (int it = 0; it < 4; it++) {
            int kr = it * 16 + rr;
            float4 v = *(const float4*)&in[(size_t)(k0 + kr) * N + n0 + cc];
            sm[kr][cc + 0] = v.x; sm[kr][cc + 1] = v.y;
            sm[kr][cc + 2] = v.z; sm[kr][cc + 3] = v.w;
        }
        __syncthreads();
        #pragma unroll
        for (int it = 0; it < 4; it++) {
            int nr = it * 16 + rr;
            b4 o;
            #pragma unroll
            for (int j = 0; j < 4; j++) o.v[j] = __float2bfloat16(sm[cc + j][nr]);
            *(b4*)&outp[(size_t)(n0 + nr) * K + k0 + cc] = o;
        }
    }
}

// ---------------------------------------------------------------------------
// LayerNorm (LN2): one block per row, 256 threads; f32 in -> bf16 out.
// ---------------------------------------------------------------------------
__global__ __launch_bounds__(256) void ln_kernel(const float* __restrict__ x,
                                                 const float* __restrict__ g,
                                                 const float* __restrict__ bta,
                                                 bf16* __restrict__ out) {
    int row = blockIdx.x;
    int t = threadIdx.x;
    const float* xr = x + (size_t)row * DD;
    float v0 = xr[t], v1 = xr[t + 256], v2 = xr[t + 512];
    float s = v0 + v1 + v2;
    float s2 = v0 * v0 + v1 * v1 + v2 * v2;
    #pragma unroll
    for (int off = 32; off > 0; off >>= 1) {
        s  += __shfl_xor(s,  off, 64);
        s2 += __shfl_xor(s2, off, 64);
    }
    __shared__ float ls[4], ls2[4];
    if ((t & 63) == 0) { ls[t >> 6] = s; ls2[t >> 6] = s2; }
    __syncthreads();
    s  = ls[0] + ls[1] + ls[2] + ls[3];
    s2 = ls2[0] + ls2[1] + ls2[2] + ls2[3];
    float mu  = s * (1.0f / DD);
    float var = s2 * (1.0f / DD) - mu * mu;
    float r = rsqrtf(var + EPS_LN);
    bf16* orow = out + (size_t)row * DD;
    orow[t]       = __float2bfloat16((v0 - mu) * r * g[t]       + bta[t]);
    orow[t + 256] = __float2bfloat16((v1 - mu) * r * g[t + 256] + bta[t + 256]);
    orow[t + 512] = __float2bfloat16((v2 - mu) * r * g[t + 512] + bta[t + 512]);
}

// ---------------------------------------------------------------------------
// 4x4 supertile swizzle.
// ---------------------------------------------------------------------------
__device__ inline void swizzle44(int bid, int nx4, int& bx, int& by) {
    int g = bid >> 4, r = bid & 15;
    bx = (g % nx4) * 4 + (r & 3);
    by = (g / nx4) * 4 + (r >> 2);
}

__device__ inline float gelu_tanh(float x) {
    float x3 = x * x * x;
    float u = 0.7978845608028654f * (x + 0.044715f * x3);
    return 0.5f * x * (1.0f + tanhf(u));
}

// ---------------------------------------------------------------------------
// TM=64 x TN=64, BK=128 GEMM — swizzled gload_lds, 2x2 wave decomposition
// (r24 keep: 16 vs 20 ds_read_b128 per K-step). SQMODE: half-row ||.||^2
// partials, sqbuf stride 48.
// ---------------------------------------------------------------------------
template <int ACT, int HAS_RES, int OUT_BF16, int SQMODE>
__global__ __launch_bounds__(256) void gemm_k128(const bf16* __restrict__ A,
                                                 const bf16* __restrict__ BT,
                                                 const float* __restrict__ bias,
                                                 const float* __restrict__ res,
                                                 void* __restrict__ Cout,
                                                 int N, int K, int nx4,
                                                 float* __restrict__ sqbuf) {
    __shared__ bf16 Asl[64][128];
    __shared__ bf16 Bsl[64][128];
    int bx, by;
    swizzle44(blockIdx.x, nx4, bx, by);
    int tid = threadIdx.x;
    int m0 = by * 64, n0 = bx * 64;
    int wave = tid >> 6, lane = tid & 63;
    int qm = lane & 15, quad = lane >> 4;
    int srow = lane >> 4;
    int chnk = lane & 15;
    int sce = (chnk ^ srow) * 8;          // i even
    int sco = (chnk ^ (srow + 4)) * 8;    // i odd
    const bf16* ag = A  + (size_t)(m0 + wave * 16 + srow) * K;
    const bf16* bg = BT + (size_t)(n0 + wave * 16 + srow) * K;
    int xr = (qm & 7) << 3;               // read-side XOR (elements)
    int wr = (wave & 1) * 32, wc = (wave >> 1) * 32;

    v4f acc[2][2] = {{{0.f,0.f,0.f,0.f},{0.f,0.f,0.f,0.f}},
                     {{0.f,0.f,0.f,0.f},{0.f,0.f,0.f,0.f}}};

    for (int k0 = 0; k0 < K; k0 += 128) {
        __syncthreads();
        #pragma unroll
        for (int i = 0; i < 4; i++) {
            int sc = (i & 1) ? sco : sce;
            gload16(ag + (size_t)(4 * i) * K + k0 + sc, &Asl[wave * 16 + 4 * i][0]);
            gload16(bg + (size_t)(4 * i) * K + k0 + sc, &Bsl[wave * 16 + 4 * i][0]);
        }
        __syncthreads();
        #pragma unroll
        for (int kc = 0; kc < 4; kc++) {
            int off = (kc * 32 + quad * 8) ^ xr;
            v8s a0 = *(const v8s*)&Asl[wr + qm][off];
            v8s a1 = *(const v8s*)&Asl[wr + 16 + qm][off];
            v8s b0 = *(const v8s*)&Bsl[wc + qm][off];
            v8s b1 = *(const v8s*)&Bsl[wc + 16 + qm][off];
            acc[0][0] = __builtin_amdgcn_mfma_f32_16x16x32_bf16(a0, b0, acc[0][0], 0, 0, 0);
            acc[0][1] = __builtin_amdgcn_mfma_f32_16x16x32_bf16(a0, b1, acc[0][1], 0, 0, 0);
            acc[1][0] = __builtin_amdgcn_mfma_f32_16x16x32_bf16(a1, b0, acc[1][0], 0, 0, 0);
            acc[1][1] = __builtin_amdgcn_mfma_f32_16x16x32_bf16(a1, b1, acc[1][1], 0, 0, 0);
        }
    }

    int col_l = lane & 15;
    if (SQMODE && n0 < 1536) {
        int hidx = n0 >> 6;               // q heads 0..11, k heads 12..23
        int half = wc >> 5;
        #pragma unroll
        for (int m = 0; m < 2; m++) {
            #pragma unroll
            for (int r = 0; r < 4; r++) {
                float hsq = 0.f;
                #pragma unroll
                for (int n = 0; n < 2; n++) {
                    float v = acc[m][n][r] + bias[n0 + wc + n * 16 + col_l];
                    hsq += v * v;
                }
                hsq += __shfl_xor(hsq, 1, 64); hsq += __shfl_xor(hsq, 2, 64);
                hsq += __shfl_xor(hsq, 4, 64); hsq += __shfl_xor(hsq, 8, 64);
                if (col_l == 0) {
                    int row = m0 + wr + m * 16 + quad * 4 + r;
                    sqbuf[(size_t)row * 48 + hidx * 2 + half] = hsq * (1.0f / 16.0f);
                }
            }
        }
        return;
    }
    #pragma unroll
    for (int n = 0; n < 2; n++) {
        int col = n0 + wc + n * 16 + col_l;
        float bcol = bias[col];
        #pragma unroll
        for (int m = 0; m < 2; m++) {
            #pragma unroll
            for (int r = 0; r < 4; r++) {
                int row = m0 + wr + m * 16 + quad * 4 + r;
                float v = acc[m][n][r] + bcol;
                if (ACT == 1) v = gelu_tanh(v);
                if (HAS_RES) v += res[(size_t)row * N + col];
                if (OUT_BF16) ((bf16*)Cout)[(size_t)row * N + col] = __float2bfloat16(v);
                else          ((float*)Cout)[(size_t)row * N + col] = v;
            }
        }
    }
}

// ---------------------------------------------------------------------------
// TM=32 x TN=64, BK=128 GEMM (proj/out, N=768) — gload_lds + XOR swizzle.
// ---------------------------------------------------------------------------
template <int ACT, int HAS_RES, int OUT_BF16>
__global__ __launch_bounds__(256) void gemm_m32_k128(const bf16* __restrict__ A,
                                                     const bf16* __restrict__ BT,
                                                     const float* __restrict__ bias,
                                                     const float* __restrict__ res,
                                                     void* __restrict__ Cout,
                                                     int N, int K, int nx4) {
    __shared__ bf16 Asl[32][128];
    __shared__ bf16 Bsl[64][128];
    int bx, by;
    swizzle44(blockIdx.x, nx4, bx, by);
    int tid = threadIdx.x;
    int m0 = by * 32, n0 = bx * 64;
    int wave = tid >> 6, lane = tid & 63;
    int qm = lane & 15, quad = lane >> 4;
    int rowh = (wave & 1) * 16;
    int colh = (wave >> 1) * 32;
    int srow = lane >> 4;
    int chnk = lane & 15;
    int sce = (chnk ^ srow) * 8;          // i even
    int sco = (chnk ^ (srow + 4)) * 8;    // i odd
    const bf16* ag = A  + (size_t)(m0 + wave * 8  + srow) * K;
    const bf16* bg = BT + (size_t)(n0 + wave * 16 + srow) * K;
    int xr = (qm & 7) << 3;

    v4f acc[2] = {{0.f,0.f,0.f,0.f},{0.f,0.f,0.f,0.f}};

    for (int k0 = 0; k0 < K; k0 += 128) {
        __syncthreads();
        #pragma unroll
        for (int i = 0; i < 2; i++) {
            int sc = (i & 1) ? sco : sce;
            gload16(ag + (size_t)(4 * i) * K + k0 + sc, &Asl[wave * 8 + 4 * i][0]);
        }
        #pragma unroll
        for (int i = 0; i < 4; i++) {
            int sc = (i & 1) ? sco : sce;
            gload16(bg + (size_t)(4 * i) * K + k0 + sc, &Bsl[wave * 16 + 4 * i][0]);
        }
        __syncthreads();
        #pragma unroll
        for (int kc = 0; kc < 4; kc++) {
            v8s a  = *(const v8s*)&Asl[rowh + qm][(kc * 32 + quad * 8) ^ xr];
            v8s b0 = *(const v8s*)&Bsl[colh + qm][(kc * 32 + quad * 8) ^ xr];
            v8s b1 = *(const v8s*)&Bsl[colh + 16 + qm][(kc * 32 + quad * 8) ^ xr];
            acc[0] = __builtin_amdgcn_mfma_f32_16x16x32_bf16(a, b0, acc[0], 0, 0, 0);
            acc[1] = __builtin_amdgcn_mfma_f32_16x16x32_bf16(a, b1, acc[1], 0, 0, 0);
        }
    }

    #pragma unroll
    for (int ct = 0; ct < 2; ct++) {
        int col = n0 + colh + ct * 16 + qm;
        float bcol = bias[col];
        #pragma unroll
        for (int r = 0; r < 4; r++) {
            int row = m0 + rowh + quad * 4 + r;
            float v = acc[ct][r] + bcol;
            if (ACT == 1) v = gelu_tanh(v);
            if (HAS_RES) v += res[(size_t)row * N + col];
            if (OUT_BF16) ((bf16*)Cout)[(size_t)row * N + col] = __float2bfloat16(v);
            else          ((float*)Cout)[(size_t)row * N + col] = v;
        }
    }
}

// ---------------------------------------------------------------------------
// Scan phase 1 (MFMA): phi(k) from proj_k + precomputed sq halves.
// StateT[d][m] = V^T @ phik ; Sk[m] = col-sum(phik).
// ---------------------------------------------------------------------------
__global__ __launch_bounds__(256) void scan_sums_mfma(const bf16* __restrict__ qkvp,
                                                      const float* __restrict__ sqbuf,
                                                      float* __restrict__ StateT,
                                                      float* __restrict__ Sk) {
    int c = blockIdx.x, h = blockIdx.y, b = blockIdx.z;
    int bh = b * HH + h;
    int t = threadIdx.x;
    __shared__ bf16 vt[64][72];   // V^T[d][s]
    __shared__ bf16 kt[64][72];   // phik^T[m][s]
    int sr = t >> 4, cq = (t & 15) * 4;
    #pragma unroll
    for (int i = 0; i < 4; i++) {
        int s = sr + 16 * i;
        size_t grow = (size_t)b * SS + c * CC + s;
        size_t rowg = grow * NQ + h * DHH;
        b4 vv = *(const b4*)&qkvp[rowg + VOFF  + cq];
        b4 kp = *(const b4*)&qkvp[rowg + PKOFF + cq];   // proj_k
        float sq = sqbuf[grow * 48 + 24 + h * 2] + sqbuf[grow * 48 + 24 + h * 2 + 1];
        #pragma unroll
        for (int j = 0; j < 4; j++) {
            vt[cq + j][s] = vv.v[j];
            kt[cq + j][s] = __float2bfloat16(
                __expf(__bfloat162float(kp.v[j]) - sq) * 0.125f + EPS_PHI);
        }
    }
    __syncthreads();
    int wave = t >> 6, lane = t & 63, qm = lane & 15, quad = lane >> 4;
    v4f acc[4] = {{0.f,0.f,0.f,0.f},{0.f,0.f,0.f,0.f},{0.f,0.f,0.f,0.f},{0.f,0.f,0.f,0.f}};
    #pragma unroll
    for (int k0 = 0; k0 < 64; k0 += 32) {
        v8s a = *(const v8s*)&vt[wave * 16 + qm][k0 + quad * 8];
        #pragma unroll
        for (int n = 0; n < 4; n++) {
            v8s bb = *(const v8s*)&kt[n * 16 + qm][k0 + quad * 8];
            acc[n] = __builtin_amdgcn_mfma_f32_16x16x32_bf16(a, bb, acc[n], 0, 0, 0);
        }
    }
    float* dst = StateT + ((size_t)bh * NC + c) * 4096;
    int col_l = lane & 15;
    #pragma unroll
    for (int n = 0; n < 4; n++)
        #pragma unroll
        for (int r = 0; r < 4; r++) {
            int d = wave * 16 + quad * 4 + r;
            dst[d * 64 + n * 16 + col_l] = acc[n][r];
        }
    {   // parallel col-sum: 4 threads per m
        int m = t >> 2, j = t & 3;
        float sum = 0.f;
        #pragma unroll
        for (int i2 = 0; i2 < 16; i2++) sum += __bfloat162float(kt[m][j * 16 + i2]);
        sum += __shfl_xor(sum, 1, 64);
        sum += __shfl_xor(sum, 2, 64);
        if (j == 0) Sk[((size_t)bh * NC + c) * 64 + m] = sum;
    }
}

// ---------------------------------------------------------------------------
// Scan phase 2: in-place EXCLUSIVE prefix over chunks (separate dispatch —
// cheap; the fused version was the r24 regression).
// ---------------------------------------------------------------------------
__global__ __launch_bounds__(256) void scan_prefix_kernel(float* __restrict__ Skv,
                                                          float* __restrict__ Sk) {
    int bh = blockIdx.y;
    int t = blockIdx.x * 256 + threadIdx.x;
    size_t base = (size_t)bh * NC * 4096 + t;
    float acc = 0.f;
    for (int c = 0; c < NC; c++) {
        float v = Skv[base + (size_t)c * 4096];
        Skv[base + (size_t)c * 4096] = acc;
        acc += v;
    }
    if (blockIdx.x == 0 && threadIdx.x < 64) {
        size_t b2 = (size_t)bh * NC * 64 + threadIdx.x;
        float a2 = 0.f;
        for (int c = 0; c < NC; c++) {
            float v = Sk[b2 + (size_t)c * 64];
            Sk[b2 + (size_t)c * 64] = a2;
            a2 += v;
        }
    }
}

// ---------------------------------------------------------------------------
// Scan phase 3 (MFMA): phi from proj + precomputed sq; den via VALU.
// acc = phiq@StateT^T + P@V; attn = acc/den.
// ---------------------------------------------------------------------------
__global__ __launch_bounds__(256) void scan_chunk_mfma(const bf16* __restrict__ qkvp,
                                                       const float* __restrict__ sqbuf,
                                                       const float* __restrict__ StateT,
                                                       const float* __restrict__ SkPre,
                                                       bf16* __restrict__ attn) {
    int c = blockIdx.x, h = blockIdx.y, b = blockIdx.z;
    int bh = b * HH + h;
    int t = threadIdx.x;
    __shared__ bf16 qs[64][72];
    __shared__ bf16 ks[64][72];
    __shared__ bf16 vt[64][72];
    __shared__ bf16 stl[64][72];
    __shared__ bf16 P[64][72];
    int sr = t >> 4, cq = (t & 15) * 4;
    const float* stg = StateT + ((size_t)bh * NC + c) * 4096;
    #pragma unroll
    for (int i = 0; i < 4; i++) {
        int s = sr + 16 * i;
        size_t grow = (size_t)b * SS + c * CC + s;
        size_t rowg = grow * NQ + h * DHH;
        b4 qp = *(const b4*)&qkvp[rowg + PQOFF + cq];   // proj_q
        b4 kp = *(const b4*)&qkvp[rowg + PKOFF + cq];   // proj_k
        b4 vv = *(const b4*)&qkvp[rowg + VOFF  + cq];
        float4 sv = *(const float4*)&stg[s * 64 + cq];
        float sqq = sqbuf[grow * 48 + h * 2]      + sqbuf[grow * 48 + h * 2 + 1];
        float sqk = sqbuf[grow * 48 + 24 + h * 2] + sqbuf[grow * 48 + 24 + h * 2 + 1];
        #pragma unroll
        for (int j = 0; j < 4; j++) {
            qs[s][cq + j] = __float2bfloat16(
                __expf(__bfloat162float(qp.v[j]) - sqq) * 0.125f + EPS_PHI);
            ks[s][cq + j] = __float2bfloat16(
                __expf(__bfloat162float(kp.v[j]) - sqk) * 0.125f + EPS_PHI);
            vt[cq + j][s] = vv.v[j];
        }
        stl[s][cq + 0] = __float2bfloat16(sv.x);
        stl[s][cq + 1] = __float2bfloat16(sv.y);
        stl[s][cq + 2] = __float2bfloat16(sv.z);
        stl[s][cq + 3] = __float2bfloat16(sv.w);
    }
    __syncthreads();
    int wave = t >> 6, lane = t & 63, qm = lane & 15, quad = lane >> 4;
    int col_l = lane & 15;
    int row0 = wave * 16;

    v4f a1[4] = {{0.f,0.f,0.f,0.f},{0.f,0.f,0.f,0.f},{0.f,0.f,0.f,0.f},{0.f,0.f,0.f,0.f}};
    #pragma unroll
    for (int k0 = 0; k0 < 64; k0 += 32) {
        v8s a = *(const v8s*)&qs[row0 + qm][k0 + quad * 8];
        #pragma unroll
        for (int n = 0; n < 4; n++) {
            v8s bb = *(const v8s*)&ks[n * 16 + qm][k0 + quad * 8];
            a1[n] = __builtin_amdgcn_mfma_f32_16x16x32_bf16(a, bb, a1[n], 0, 0, 0);
        }
    }
    float denl[4] = {0.f, 0.f, 0.f, 0.f};
    #pragma unroll
    for (int n = 0; n < 4; n++)
        #pragma unroll
        for (int r = 0; r < 4; r++) {
            int row = row0 + quad * 4 + r;
            int col = n * 16 + col_l;
            float v = (col <= row) ? a1[n][r] : 0.f;
            P[row][col] = __float2bfloat16(v);
            denl[r] += v;
        }
    {   // + phiq . SkPre (cross-chunk part); lane handles m = qm*4..qm*4+3
        const float* skp = SkPre + ((size_t)bh * NC + c) * 64;
        float4 sk4 = *(const float4*)&skp[qm * 4];
        #pragma unroll
        for (int r = 0; r < 4; r++) {
            int row = row0 + quad * 4 + r;
            b4 qv = *(const b4*)&qs[row][qm * 4];
            denl[r] += __bfloat162float(qv.v[0]) * sk4.x
                     + __bfloat162float(qv.v[1]) * sk4.y
                     + __bfloat162float(qv.v[2]) * sk4.z
                     + __bfloat162float(qv.v[3]) * sk4.w;
        }
    }
    #pragma unroll
    for (int r = 0; r < 4; r++) {
        denl[r] += __shfl_xor(denl[r], 1, 64);
        denl[r] += __shfl_xor(denl[r], 2, 64);
        denl[r] += __shfl_xor(denl[r], 4, 64);
        denl[r] += __shfl_xor(denl[r], 8, 64);
    }
    v4f acc[4] = {{0.f,0.f,0.f,0.f},{0.f,0.f,0.f,0.f},{0.f,0.f,0.f,0.f},{0.f,0.f,0.f,0.f}};
    #pragma unroll
    for (int k0 = 0; k0 < 64; k0 += 32) {
        v8s aq = *(const v8s*)&qs[row0 + qm][k0 + quad * 8];
        v8s ap = *(const v8s*)&P [row0 + qm][k0 + quad * 8];
        #pragma unroll
        for (int n = 0; n < 4; n++) {
            v8s b1 = *(const v8s*)&stl[n * 16 + qm][k0 + quad * 8];
            v8s b2 = *(const v8s*)&vt [n * 16 + qm][k0 + quad * 8];
            acc[n] = __builtin_amdgcn_mfma_f32_16x16x32_bf16(aq, b1, acc[n], 0, 0, 0);
            acc[n] = __builtin_amdgcn_mfma_f32_16x16x32_bf16(ap, b2, acc[n], 0, 0, 0);
        }
    }
    #pragma unroll
    for (int n = 0; n < 4; n++)
        #pragma unroll
        for (int r = 0; r < 4; r++) {
            int srow = row0 + quad * 4 + r;
            int d = n * 16 + col_l;
            attn[((size_t)b * SS + c * CC + srow) * DD + h * DHH + d] =
                __float2bfloat16(acc[n][r] / denl[r]);
        }
}

// ---------------------------------------------------------------------------
extern "C" void kernel_launch(void* const* d_in, const int* in_sizes, int n_in,
                              void* d_out, int out_size, void* d_ws, size_t ws_size,
                              hipStream_t stream) {
    const float* x      = (const float*)d_in[0];
    const float* ln1_g  = (const float*)d_in[1];
    const float* ln1_b  = (const float*)d_in[2];
    const float* w_attn = (const float*)d_in[3];
    const float* b_attn = (const float*)d_in[4];
    const float* w_feat = (const float*)d_in[5];
    const float* w_proj = (const float*)d_in[6];
    const float* b_proj = (const float*)d_in[7];
    const float* ln2_g  = (const float*)d_in[8];
    const float* ln2_b  = (const float*)d_in[9];
    const float* w_fc   = (const float*)d_in[10];
    const float* b_fc   = (const float*)d_in[11];
    const float* w_out  = (const float*)d_in[12];
    const float* b_out  = (const float*)d_in[13];
    float* out = (float*)d_out;

    // f32 region
    float* ws = (float*)d_ws;
    size_t off = 0;
    float* buf_x1   = ws + off; off += (size_t)BS * DD;            // 1.57M f32
    float* buf_sk   = ws + off; off += (size_t)BB * HH * NC * MM;  // 24.6K
    float* bias_ext = ws + off; off += NQ;
    float* buf_sq   = ws + off; off += (size_t)BS * 48;            // half-row ||.||^2
    // bf16 region (16B-aligned: preceding counts are multiples of 4)
    bf16* wb = (bf16*)(ws + off);
    size_t boff = 0;
    bf16* buf_qkvp    = wb + boff; boff += (size_t)BS * NQ;        // 7.86M bf16
    bf16* buf_a_bf    = wb + boff; boff += (size_t)BS * DD;
    bf16* buf_attn_bf = wb + boff; boff += (size_t)BS * DD;
    bf16* wext_t      = wb + boff; boff += (size_t)NQ * DD;
    bf16* wproj_t     = wb + boff; boff += (size_t)DD * DD;
    bf16* wfc_t       = wb + boff; boff += (size_t)DFF * DD;
    bf16* wout_t      = wb + boff; boff += (size_t)DD * DFF;
    // Aliases: StateT (1.57M f32) over buf_x1 (x1 written after scan);
    //          fc bf16 (6.29M) over buf_qkvp head (qkvp dead after scan).
    float* buf_skv   = buf_x1;
    bf16*  buf_fc_bf = buf_qkvp;

    // 0a) FAVOR+ fused cols + bias
    feat_kernel<<<289, 256, 0, stream>>>(w_attn, b_attn, w_feat, wext_t, bias_ext);
    // 0b) LN1 + transposes
    prep_main<<<3776, 256, 0, stream>>>(x, ln1_g, ln1_b,
                                        w_attn, w_proj, w_fc, w_out,
                                        buf_a_bf, wext_t, wproj_t, wfc_t, wout_t);
    // 1) [qkv | proj] = a @ W_ext + bias_ext; q/k head tiles -> sq halves
    gemm_k128<0, 0, 1, 1><<<1920, 256, 0, stream>>>(
        buf_a_bf, wext_t, bias_ext, nullptr, buf_qkvp, NQ, DD, 15, buf_sq);
    // 2a) per-chunk sums (MFMA)
    scan_sums_mfma<<<dim3(NC, HH, BB), 256, 0, stream>>>(buf_qkvp, buf_sq, buf_skv, buf_sk);
    // 2b) exclusive prefix over chunks
    scan_prefix_kernel<<<dim3(4096 / 256, BB * HH), 256, 0, stream>>>(buf_skv, buf_sk);
    // 2c) per-chunk masked-MFMA scan -> attn
    scan_chunk_mfma<<<dim3(NC, HH, BB), 256, 0, stream>>>(
        buf_qkvp, buf_sq, buf_skv, buf_sk, buf_attn_bf);
    // 3) x1 = x + attn @ w_proj + b_proj
    gemm_m32_k128<0, 1, 0><<<768, 256, 0, stream>>>(
        buf_attn_bf, wproj_t, b_proj, x, buf_x1, DD, DD, 3);
    // 4) m = LN2(x1) -> bf16
    ln_kernel<<<BS, 256, 0, stream>>>(buf_x1, ln2_g, ln2_b, buf_a_bf);
    // 5) fc = gelu(m @ w_fc + b_fc) -> bf16
    gemm_k128<1, 0, 1, 0><<<1536, 256, 0, stream>>>(
        buf_a_bf, wfc_t, b_fc, nullptr, buf_fc_bf, DFF, DD, 12, nullptr);
    // 6) out = x1 + fc @ w_out + b_out
    gemm_m32_k128<0, 1, 0><<<768, 256, 0, stream>>>(
        buf_fc_bf, wout_t, b_out, buf_x1, out, DD, DFF, 3);
}